// Round 2
// baseline (328.216 us; speedup 1.0000x reference)
//
#include <hip/hip_runtime.h>
#include <hip/hip_bf16.h>
#include <stdint.h>

// Problem sizes (compile-time)
static constexpr int BATCH = 32768;
static constexpr int DIN   = 512;
static constexpr int DHID  = 1024;
static constexpr int DOUT  = 2048;

typedef __bf16 bf16x8 __attribute__((ext_vector_type(8)));
typedef float  f32x4  __attribute__((ext_vector_type(4)));

// fp32 -> bf16 round-to-nearest-even (matches HW convert for normals)
__device__ __forceinline__ unsigned short f2bf(float f) {
    unsigned int u = __float_as_uint(f);
    u += 0x7FFFu + ((u >> 16) & 1u);
    return (unsigned short)(u >> 16);
}

// async global->LDS, 16B per lane. LDS dest is wave-uniform base; HW scatters lane i to base + 16*i.
__device__ __forceinline__ void gload_lds16(const void* g, void* l) {
    __builtin_amdgcn_global_load_lds((__attribute__((address_space(1))) void*)g,
                                     (__attribute__((address_space(3))) void*)l,
                                     16, 0, 0);
}

// ---------------------------------------------------------------------------
// Kernel 1: convert x, l1_w, weight fp32 -> bf16 into workspace
// ---------------------------------------------------------------------------
__global__ __launch_bounds__(256) void cvt_kernel(
    const float4* __restrict__ x, const float4* __restrict__ w1, const float4* __restrict__ w2,
    ushort4* __restrict__ xb, ushort4* __restrict__ w1b, ushort4* __restrict__ w2b) {
    const size_t NX  = (size_t)BATCH * DIN  / 4;   // 4,194,304
    const size_t NW1 = (size_t)DHID  * DIN  / 4;   //   131,072
    const size_t NW2 = (size_t)DOUT  * DHID / 4;   //   524,288
    size_t g = (size_t)blockIdx.x * blockDim.x + threadIdx.x;
    const float4* s; ushort4* d; size_t i;
    if (g < NX)                  { s = x;  d = xb;  i = g; }
    else if (g < NX + NW1)       { s = w1; d = w1b; i = g - NX; }
    else if (g < NX + NW1 + NW2) { s = w2; d = w2b; i = g - NX - NW1; }
    else return;
    float4 v = s[i];
    ushort4 o;
    o.x = f2bf(v.x); o.y = f2bf(v.y); o.z = f2bf(v.z); o.w = f2bf(v.w);
    d[i] = o;
}

// ---------------------------------------------------------------------------
// GEMM core pattern (m97 structure): C[128x128] = A[M,K] * Bw[N,K]^T per block.
// 256 threads = 4 waves in 2x2; each wave computes 64x64 via 4x4 MFMA 16x16x32.
// BK=32; A/B tiles staged with global_load_lds width 16.
// ---------------------------------------------------------------------------

// GEMM1: h = x * l1_w^T + l1_b, output bf16 [BATCH, DHID]
__global__ __launch_bounds__(256) void gemm1_kernel(
    const unsigned short* __restrict__ A,   // x  bf16 [BATCH, DIN]
    const unsigned short* __restrict__ Bw,  // l1_w bf16 [DHID, DIN]
    const float* __restrict__ l1b,          // [DHID]
    unsigned short* __restrict__ H) {       // out bf16 [BATCH, DHID]
    constexpr int K = DIN;
    __shared__ __align__(16) unsigned short sA[128 * 32];
    __shared__ __align__(16) unsigned short sB[128 * 32];

    const int tid  = threadIdx.x;
    const int lane = tid & 63;
    const int wid  = tid >> 6;
    const int wr = wid >> 1, wc = wid & 1;
    const int r = lane & 15, q = lane >> 4;
    const int blockM = blockIdx.x * 128;
    const int blockN = blockIdx.y * 128;

    // staging: wave wid loads chunks {2*wid, 2*wid+1} (16 rows x 32 cols each) of A and B tiles
    const int c0    = wid * 2;
    const int arow0 = c0 * 16 + (lane >> 2);
    const int acol  = (lane & 3) * 8;
    const size_t abase = (size_t)(blockM + arow0) * K + acol;
    const size_t bbase = (size_t)(blockN + arow0) * K + acol;

    f32x4 acc[4][4];
#pragma unroll
    for (int mt = 0; mt < 4; ++mt)
#pragma unroll
        for (int nt = 0; nt < 4; ++nt) { f32x4 z = {0.f, 0.f, 0.f, 0.f}; acc[mt][nt] = z; }

    for (int k0 = 0; k0 < K; k0 += 32) {
        gload_lds16(A  + abase + k0,          sA + c0 * 512);
        gload_lds16(A  + abase + 16 * K + k0, sA + c0 * 512 + 512);
        gload_lds16(Bw + bbase + k0,          sB + c0 * 512);
        gload_lds16(Bw + bbase + 16 * K + k0, sB + c0 * 512 + 512);
        __syncthreads();
        bf16x8 af[4], bf[4];
#pragma unroll
        for (int mt = 0; mt < 4; ++mt) af[mt] = *(const bf16x8*)&sA[(wr * 64 + mt * 16 + r) * 32 + q * 8];
#pragma unroll
        for (int nt = 0; nt < 4; ++nt) bf[nt] = *(const bf16x8*)&sB[(wc * 64 + nt * 16 + r) * 32 + q * 8];
#pragma unroll
        for (int mt = 0; mt < 4; ++mt)
#pragma unroll
            for (int nt = 0; nt < 4; ++nt)
                acc[mt][nt] = __builtin_amdgcn_mfma_f32_16x16x32_bf16(af[mt], bf[nt], acc[mt][nt], 0, 0, 0);
        __syncthreads();
    }

    // Epilogue: +bias, convert, store. C/D layout: col = lane&15, row = q*4+reg.
    const int colBase = blockN + wc * 64;
    const int rowBase = blockM + wr * 64;
    float bv[4];
#pragma unroll
    for (int nt = 0; nt < 4; ++nt) bv[nt] = l1b[colBase + nt * 16 + r];
#pragma unroll
    for (int mt = 0; mt < 4; ++mt) {
        const int row0 = rowBase + mt * 16 + q * 4;
#pragma unroll
        for (int nt = 0; nt < 4; ++nt) {
            const int col = colBase + nt * 16 + r;
#pragma unroll
            for (int reg = 0; reg < 4; ++reg)
                H[(size_t)(row0 + reg) * DHID + col] = f2bf(acc[mt][nt][reg] + bv[nt]);
        }
    }
}

// GEMM2: scores = H * weight^T + bias, fused row-max over this block's 128 cols.
// Writes per-(row, 64-col-chunk) maxima: partials[row*32 + blockIdx.y*2 + wc]
__global__ __launch_bounds__(256) void gemm2_kernel(
    const unsigned short* __restrict__ A,   // H bf16 [BATCH, DHID]
    const unsigned short* __restrict__ Bw,  // weight bf16 [DOUT, DHID]
    const float* __restrict__ bias,         // [DOUT]
    float* __restrict__ partials) {         // [BATCH, 32]
    constexpr int K = DHID;
    __shared__ __align__(16) unsigned short sA[128 * 32];
    __shared__ __align__(16) unsigned short sB[128 * 32];

    const int tid  = threadIdx.x;
    const int lane = tid & 63;
    const int wid  = tid >> 6;
    const int wr = wid >> 1, wc = wid & 1;
    const int r = lane & 15, q = lane >> 4;
    const int blockM = blockIdx.x * 128;
    const int blockN = blockIdx.y * 128;

    const int c0    = wid * 2;
    const int arow0 = c0 * 16 + (lane >> 2);
    const int acol  = (lane & 3) * 8;
    const size_t abase = (size_t)(blockM + arow0) * K + acol;
    const size_t bbase = (size_t)(blockN + arow0) * K + acol;

    f32x4 acc[4][4];
#pragma unroll
    for (int mt = 0; mt < 4; ++mt)
#pragma unroll
        for (int nt = 0; nt < 4; ++nt) { f32x4 z = {0.f, 0.f, 0.f, 0.f}; acc[mt][nt] = z; }

    for (int k0 = 0; k0 < K; k0 += 32) {
        gload_lds16(A  + abase + k0,          sA + c0 * 512);
        gload_lds16(A  + abase + 16 * K + k0, sA + c0 * 512 + 512);
        gload_lds16(Bw + bbase + k0,          sB + c0 * 512);
        gload_lds16(Bw + bbase + 16 * K + k0, sB + c0 * 512 + 512);
        __syncthreads();
        bf16x8 af[4], bf[4];
#pragma unroll
        for (int mt = 0; mt < 4; ++mt) af[mt] = *(const bf16x8*)&sA[(wr * 64 + mt * 16 + r) * 32 + q * 8];
#pragma unroll
        for (int nt = 0; nt < 4; ++nt) bf[nt] = *(const bf16x8*)&sB[(wc * 64 + nt * 16 + r) * 32 + q * 8];
#pragma unroll
        for (int mt = 0; mt < 4; ++mt)
#pragma unroll
            for (int nt = 0; nt < 4; ++nt)
                acc[mt][nt] = __builtin_amdgcn_mfma_f32_16x16x32_bf16(af[mt], bf[nt], acc[mt][nt], 0, 0, 0);
        __syncthreads();
    }

    // Epilogue: +bias, max over this wave's 64 cols, quad-lane reduce, write partial.
    const int colBase = blockN + wc * 64;
    const int rowBase = blockM + wr * 64;
    float bv[4];
#pragma unroll
    for (int nt = 0; nt < 4; ++nt) bv[nt] = bias[colBase + nt * 16 + r];

    float mx[4][4];  // [mt][reg]
#pragma unroll
    for (int mt = 0; mt < 4; ++mt)
#pragma unroll
        for (int reg = 0; reg < 4; ++reg) {
            float v = acc[mt][0][reg] + bv[0];
            v = fmaxf(v, acc[mt][1][reg] + bv[1]);
            v = fmaxf(v, acc[mt][2][reg] + bv[2]);
            v = fmaxf(v, acc[mt][3][reg] + bv[3]);
            mx[mt][reg] = v;
        }
    // reduce across the 16 lanes of a quad (these hold cols 0..15 of the same rows)
#pragma unroll
    for (int off = 1; off < 16; off <<= 1)
#pragma unroll
        for (int mt = 0; mt < 4; ++mt)
#pragma unroll
            for (int reg = 0; reg < 4; ++reg)
                mx[mt][reg] = fmaxf(mx[mt][reg], __shfl_xor(mx[mt][reg], off));

    if (r == 0) {
#pragma unroll
        for (int mt = 0; mt < 4; ++mt)
#pragma unroll
            for (int reg = 0; reg < 4; ++reg) {
                const int row = rowBase + mt * 16 + q * 4 + reg;
                partials[(size_t)row * 32 + blockIdx.y * 2 + wc] = mx[mt][reg];
            }
    }
}

// ---------------------------------------------------------------------------
// Kernel 4: reduce 32 partials per row -> final max
// ---------------------------------------------------------------------------
__global__ __launch_bounds__(256) void reduce_kernel(
    const float4* __restrict__ partials, float* __restrict__ out) {
    const int row = blockIdx.x * blockDim.x + threadIdx.x;  // exactly BATCH threads
    const float4* p = partials + (size_t)row * 8;
    float m = -INFINITY;
#pragma unroll
    for (int i = 0; i < 8; ++i) {
        float4 v = p[i];
        m = fmaxf(m, fmaxf(fmaxf(v.x, v.y), fmaxf(v.z, v.w)));
    }
    out[row] = m;
}

// ---------------------------------------------------------------------------
extern "C" void kernel_launch(void* const* d_in, const int* in_sizes, int n_in,
                              void* d_out, int out_size, void* d_ws, size_t ws_size,
                              hipStream_t stream) {
    const float* x   = (const float*)d_in[0];
    const float* l1w = (const float*)d_in[1];
    const float* l1b = (const float*)d_in[2];
    const float* w2  = (const float*)d_in[3];
    const float* b2  = (const float*)d_in[4];
    float* out = (float*)d_out;

    char* ws = (char*)d_ws;
    // workspace layout (bytes)
    unsigned short* xb  = (unsigned short*)(ws);                 // 32 MB  x  bf16
    unsigned short* w1b = (unsigned short*)(ws + 33554432);      //  1 MB  l1_w bf16
    unsigned short* w2b = (unsigned short*)(ws + 34603008);      //  4 MB  weight bf16
    unsigned short* hb  = (unsigned short*)(ws + 38797312);      // 64 MB  h bf16
    float* partials     = (float*)(ws + 105906176);              //  4 MB  [BATCH,32]

    // 1) fp32 -> bf16 converts (covers x, l1_w, weight; 4,849,664 float4 groups)
    cvt_kernel<<<18944, 256, 0, stream>>>(
        (const float4*)x, (const float4*)l1w, (const float4*)w2,
        (ushort4*)xb, (ushort4*)w1b, (ushort4*)w2b);

    // 2) h = x @ l1_w^T + l1_b   [32768, 1024]
    gemm1_kernel<<<dim3(BATCH / 128, DHID / 128), 256, 0, stream>>>(xb, w1b, l1b, hb);

    // 3) scores = h @ weight^T + bias, fused per-block row-max
    gemm2_kernel<<<dim3(BATCH / 128, DOUT / 128), 256, 0, stream>>>(hb, w2b, b2, partials);

    // 4) final max over 32 partials per row
    reduce_kernel<<<BATCH / 256, 256, 0, stream>>>((const float4*)partials, out);
}